// Round 1
// baseline (1455.845 us; speedup 1.0000x reference)
//
#include <hip/hip_runtime.h>

// CRF Viterbi decode: B=64, T=1024, K=256.
// emissions [B,T,K] f32, transitions [K,K] f32 (prev->next). out [B,T] f32 tags.
//
// Path A (M 64MB + gidp 8.4MB + bp 16.75MB + maps 256KB + exits 4KB ~ 89.4MB):
//   1. crf_forward_states : single-barrier restructure. Each wave owns 16
//      columns; each lane = (column, 64-prev chunk) with the 64 trans values
//      in registers (v_pk_add_f32 packed adds). Cross-chunk reduce = 2-hop
//      shfl_xor butterfly (no serial 4-wave reducer, no s_partial round-trip).
//      State double-buffered in LDS -> ONE __syncthreads per step. Chunk
//      stride 132 floats staggers the 4 broadcast addrs of each ds_read_b128
//      onto banks {0,8,16,24}+4k (conflict-free); first 3 float4 of each
//      half replicated so reads are base+imm (no per-read addr VALU, no
//      modular wrap). gid (lowest 32-group attaining max) computed DEFERRED
//      one step later (r10: in-line gid sat on the pre-barrier chain).
//   2. crf_bp_gid         : 4 waves/block + gid prefetch pipeline (unchanged).
//   3. crf_seg_maps / crf_compose / crf_emit : proven segmented chase.
// Path B: forward(no gid) + bp_matrix full scan + chase.  Path C: zero.

#define CRF_B 64
#define CRF_T 1024
#define CRF_K 256
#define NSEG  16
#define SEGLEN 64

// ---------------------------------------------------------------------------
// Forward
// ---------------------------------------------------------------------------

typedef float f32x2 __attribute__((ext_vector_type(2)));

__device__ __forceinline__ f32x2 pk_add(f32x2 a, f32x2 b) {
    f32x2 d;
    asm("v_pk_add_f32 %0, %1, %2" : "=v"(d) : "v"(a), "v"(b));
    return d;
}

#define CHUNK_F 132                 // floats per 64-prev chunk (stagger+replica)
#define BUF_F   (4 * CHUNK_F)       // 528 floats per state buffer

__global__ __launch_bounds__(1024, 4) void crf_forward_states(
    const float* __restrict__ em, const float* __restrict__ trans,
    float* __restrict__ M, unsigned char* __restrict__ gidp)
{
    const int b    = blockIdx.x;
    const int tid  = threadIdx.x;
    const int w    = tid >> 6;        // wave 0..15 -> columns w*16..w*16+15
    const int lane = tid & 63;
    const int l    = lane & 15;       // column-within-wave
    const int q    = lane >> 4;       // prev chunk 0..3 (64 prevs each)
    const int c    = (w << 4) + l;    // owned column
    const bool own = (q == 0);

    __shared__ __align__(16) float sbuf[2][BUF_F];   // double-buffered state

    // Trans fragment: 64 values T[p][c]; reg order matches the rotated reads.
    // tr[2k],tr[2k+1]   <-> p = 64q + 4*((q+k)&7) + {0..3}        (group 2q)
    // tr[16+2k..]       <-> p = 64q + 32 + 4*((q+k)&7) + {0..3}   (group 2q+1)
    f32x2 tr[32];
#pragma unroll
    for (int k = 0; k < 8; ++k) {
        const int p0 = (q << 6) + 4 * ((q + k) & 7);
        const float* tp0 = trans + (size_t)p0 * CRF_K + c;
        tr[2*k+0].x = tp0[0];
        tr[2*k+0].y = tp0[CRF_K];
        tr[2*k+1].x = tp0[2 * CRF_K];
        tr[2*k+1].y = tp0[3 * CRF_K];
        const float* tp1 = tp0 + 32 * CRF_K;
        tr[16+2*k+0].x = tp1[0];
        tr[16+2*k+0].y = tp1[CRF_K];
        tr[16+2*k+1].x = tp1[2 * CRF_K];
        tr[16+2*k+1].y = tp1[3 * CRF_K];
    }

    const float* emb = em + (size_t)b * CRF_T * CRF_K;

    // state[0] = em[0], written in replicated layout
    if (tid < CRF_K) {
        const int cid = tid >> 6, h = (tid >> 5) & 1, pos = tid & 31;
        const int a0  = CHUNK_F * cid + 64 * h + pos;
        float v = emb[tid];
        sbuf[0][a0] = v;
        if (pos < 12) sbuf[0][a0 + 32] = v;      // replica for wrap reads
    }
    float e_cur = own ? emb[CRF_K + c] : 0.0f;   // emission for t = 1
    __syncthreads();

    // own-lane state-write slot (replicated layout)
    const int wcid = c >> 6, wh = (c >> 5) & 1, wpos = c & 31;
    const int wa   = CHUNK_F * wcid + 64 * wh + wpos;

    float* mptr = M + ((size_t)CRF_B + b) * CRF_K + c;              // row t=1
    unsigned char* gptr = gidp
        ? gidp + ((size_t)CRF_B + b) * 128 + (w << 3) + (l >> 1)    // row t=1
        : nullptr;

    float pm0 = 0.0f, pm1 = 0.0f, pbv = 0.0f;    // deferred-gid state
    int cb = 0;

    for (int t = 1; t < CRF_T; ++t) {
        // deferred gid for step t-1: 3 shuffle hops overlap this step's reads
        if (gptr && t > 1) {
            int g = (pm1 == pbv) ? ((q << 1) | 1) : 8;
            if (pm0 == pbv) g = q << 1;
            g = min(g, __shfl_xor(g, 16, 64));
            g = min(g, __shfl_xor(g, 32, 64));
            int go = __shfl_down(g, 1, 64);
            if (own && !(l & 1))
                *gptr = (unsigned char)(g | (go << 4));
            gptr += CRF_B * 128;
        }

        float e_next = 0.0f;
        if (own && t + 1 < CRF_T)
            e_next = emb[(size_t)(t + 1) * CRF_K + c];

        // chunk q at float4 index 33q; reads sp[q+k] / sp[16+q+k] are
        // base + imm, banks (8q+4k)%32 -> conflict-free across q
        const float4* sp = (const float4*)(sbuf[cb]) + 33 * q;

        float m0 = -INFINITY, m1 = -INFINITY;
#pragma unroll
        for (int k = 0; k < 8; ++k) {
            float4 sv = sp[q + k];
            f32x2 lo; lo.x = sv.x; lo.y = sv.y;
            f32x2 hi; hi.x = sv.z; hi.y = sv.w;
            f32x2 r0 = pk_add(lo, tr[2*k]);
            f32x2 r1 = pk_add(hi, tr[2*k+1]);
            m0 = fmaxf(fmaxf(r0.x, r0.y), m0);   // v_max3_f32
            m0 = fmaxf(fmaxf(r1.x, r1.y), m0);
        }
#pragma unroll
        for (int k = 0; k < 8; ++k) {
            float4 sv = sp[16 + q + k];
            f32x2 lo; lo.x = sv.x; lo.y = sv.y;
            f32x2 hi; hi.x = sv.z; hi.y = sv.w;
            f32x2 r0 = pk_add(lo, tr[16+2*k]);
            f32x2 r1 = pk_add(hi, tr[16+2*k+1]);
            m1 = fmaxf(fmaxf(r0.x, r0.y), m1);
            m1 = fmaxf(fmaxf(r1.x, r1.y), m1);
        }

        float bv = fmaxf(m0, m1);
        bv = fmaxf(bv, __shfl_xor(bv, 16, 64));
        bv = fmaxf(bv, __shfl_xor(bv, 32, 64));

        float* nb = sbuf[cb ^ 1];
        if (own) {
            *mptr = bv;                          // PRE-emission (M layout kept)
            float sv = bv + e_cur;
            nb[wa] = sv;
            if (wpos < 12) nb[wa + 32] = sv;     // replica
        }
        pm0 = m0; pm1 = m1; pbv = bv;
        __syncthreads();                          // the ONLY barrier per step
        e_cur = e_next;
        mptr += CRF_B * CRF_K;
        cb ^= 1;
    }

    // flush gid for t = CRF_T-1
    if (gptr) {
        int g = (pm1 == pbv) ? ((q << 1) | 1) : 8;
        if (pm0 == pbv) g = q << 1;
        g = min(g, __shfl_xor(g, 16, 64));
        g = min(g, __shfl_xor(g, 32, 64));
        int go = __shfl_down(g, 1, 64);
        if (own && !(l & 1))
            *gptr = (unsigned char)(g | (go << 4));
    }
}

// ---------------------------------------------------------------------------
// bp via gid: 512 blocks (b x cg4 x ts2) x 256 thr (4 waves, t1 stride 4).
// 64KB transposed trans tile; gid byte for next iteration prefetched.
// ---------------------------------------------------------------------------

#define BPG_CHUNK(j) { \
    float4 mm = M4[j]; float4 ee = E4[j]; \
    float s0 = mm.x + ee.x, s1 = mm.y + ee.y; \
    float s2 = mm.z + ee.z, s3 = mm.w + ee.w; \
    float t0v = s_tile[base + 4*(j) + 0][lane]; \
    float t1v = s_tile[base + 4*(j) + 1][lane]; \
    float t2v = s_tile[base + 4*(j) + 2][lane]; \
    float t3v = s_tile[base + 4*(j) + 3][lane]; \
    float v0 = s0 + t0v; if (v0 > best) { best = v0; arg = base + 4*(j); } \
    float v1 = s1 + t1v; if (v1 > best) { best = v1; arg = base + 4*(j) + 1; } \
    float v2 = s2 + t2v; if (v2 > best) { best = v2; arg = base + 4*(j) + 2; } \
    float v3 = s3 + t3v; if (v3 > best) { best = v3; arg = base + 4*(j) + 3; } }

#define BPG_CHUNK0(j) { \
    float4 ee = E4[j]; \
    float t0v = s_tile[base + 4*(j) + 0][lane]; \
    float t1v = s_tile[base + 4*(j) + 1][lane]; \
    float t2v = s_tile[base + 4*(j) + 2][lane]; \
    float t3v = s_tile[base + 4*(j) + 3][lane]; \
    float v0 = ee.x + t0v; if (v0 > best) { best = v0; arg = base + 4*(j); } \
    float v1 = ee.y + t1v; if (v1 > best) { best = v1; arg = base + 4*(j) + 1; } \
    float v2 = ee.z + t2v; if (v2 > best) { best = v2; arg = base + 4*(j) + 2; } \
    float v3 = ee.w + t3v; if (v3 > best) { best = v3; arg = base + 4*(j) + 3; } }

__global__ __launch_bounds__(256) void crf_bp_gid(
    const float* __restrict__ M, const float* __restrict__ em,
    const float* __restrict__ trans, const unsigned char* __restrict__ gidp,
    unsigned char* __restrict__ bp)
{
    const int b    = blockIdx.x >> 3;
    const int cg   = (blockIdx.x >> 1) & 3;
    const int ts   = blockIdx.x & 1;
    const int tid  = threadIdx.x;
    const int lane = tid & 63;
    const int w    = tid >> 6;      // wave 0..3

    __shared__ float s_tile[CRF_K][64];   // 64 KB: s_tile[prev][col]

    const int k0 = cg * 64;
    for (int idx = tid; idx < CRF_K * 64; idx += 256) {
        const int p = idx >> 6, cc = idx & 63;
        s_tile[p][cc] = trans[(size_t)p * CRF_K + k0 + cc];
    }
    __syncthreads();

    const int t_lo = ts * 512;
    const int t_hi = ts ? (CRF_T - 1) : 512;
    const int half = (k0 >> 1) + (lane >> 1);
    const int odd  = lane & 1;

    int t1 = t_lo + w;
    if (t1 >= t_hi) return;
    unsigned char gb = gidp[((size_t)(t1 + 1) * CRF_B + b) * 128 + half];

    for (; t1 < t_hi; t1 += 4) {
        const int tn = t1 + 4;
        unsigned char gb_next = 0;
        if (tn < t_hi)                         // prefetch next gid byte
            gb_next = gidp[((size_t)(tn + 1) * CRF_B + b) * 128 + half];

        const int g    = odd ? ((gb >> 4) & 7) : (gb & 7);
        const int base = g << 5;
        const float4* E4 =
            (const float4*)(em + ((size_t)b * CRF_T + t1) * CRF_K + base);
        float best = -INFINITY; int arg = base;
        if (t1 == 0) {                         // state[0] = em[0]
            BPG_CHUNK0(0) BPG_CHUNK0(1) BPG_CHUNK0(2) BPG_CHUNK0(3)
            BPG_CHUNK0(4) BPG_CHUNK0(5) BPG_CHUNK0(6) BPG_CHUNK0(7)
        } else {
            const float4* M4 =
                (const float4*)(M + ((size_t)t1 * CRF_B + b) * CRF_K + base);
            BPG_CHUNK(0) BPG_CHUNK(1) BPG_CHUNK(2) BPG_CHUNK(3)
            BPG_CHUNK(4) BPG_CHUNK(5) BPG_CHUNK(6) BPG_CHUNK(7)
        }
        bp[((size_t)b * (CRF_T - 1) + t1) * CRF_K + k0 + lane] =
            (unsigned char)arg;
        gb = gb_next;
    }
}

// ---------------------------------------------------------------------------
// Fallback-B backpointers: full-scan bp_matrix (proven), state = M+em.
// ---------------------------------------------------------------------------

__global__ __launch_bounds__(1024, 2) void crf_bp_matrix(
    const float* __restrict__ M, const float* __restrict__ em,
    const float* __restrict__ trans, unsigned char* __restrict__ bp)
{
    const int b   = blockIdx.x >> 4;
    const int seg = blockIdx.x & 15;
    const int tid = threadIdx.x;
    const int g   = tid >> 8;      // 0..3
    const int k   = tid & 255;

    __shared__ __align__(16) float s_row[CRF_K];
    __shared__ float s_pv[4][CRF_K];
    __shared__ int   s_pi[4][CRF_K];

    const int pbase = g * 64;
    float4 tr[16];
#pragma unroll
    for (int i = 0; i < 16; ++i) {
        const int p = pbase + 4 * i;
        tr[i].x = trans[(p + 0) * CRF_K + k];
        tr[i].y = trans[(p + 1) * CRF_K + k];
        tr[i].z = trans[(p + 2) * CRF_K + k];
        tr[i].w = trans[(p + 3) * CRF_K + k];
    }

    const int t_lo = seg * SEGLEN;
    const int t_hi = min(t_lo + SEGLEN, CRF_T - 1);
    unsigned char* bpb = bp + (size_t)b * (CRF_T - 1) * CRF_K;

    for (int t1 = t_lo; t1 < t_hi; ++t1) {
        if (tid < CRF_K) {
            float ev = em[((size_t)b * CRF_T + t1) * CRF_K + tid];
            float sv = ev;
            if (t1 > 0) sv = M[((size_t)t1 * CRF_B + b) * CRF_K + tid] + ev;
            s_row[tid] = sv;
        }
        __syncthreads();

        float best = -INFINITY;
        int   arg  = pbase;
        const float4* spp = (const float4*)(s_row + pbase);
#pragma unroll
        for (int i = 0; i < 16; ++i) {
            float4 st = spp[i];
            const int p = pbase + 4 * i;
            float s0 = st.x + tr[i].x;
            float s1 = st.y + tr[i].y;
            float s2 = st.z + tr[i].z;
            float s3 = st.w + tr[i].w;
            if (s0 > best) { best = s0; arg = p; }
            if (s1 > best) { best = s1; arg = p + 1; }
            if (s2 > best) { best = s2; arg = p + 2; }
            if (s3 > best) { best = s3; arg = p + 3; }
        }
        s_pv[g][k] = best;
        s_pi[g][k] = arg;
        __syncthreads();
        if (tid < CRF_K) {
            float bv = s_pv[0][tid];
            int   ba = s_pi[0][tid];
#pragma unroll
            for (int j = 1; j < 4; ++j) {
                float v = s_pv[j][tid];
                if (v > bv) { bv = v; ba = s_pi[j][tid]; }
            }
            bpb[(size_t)t1 * CRF_K + tid] = (unsigned char)ba;
        }
        __syncthreads();
    }
}

// ---------------------------------------------------------------------------
// Segmented chase (proven): seg_maps -> compose -> emit.
// ---------------------------------------------------------------------------

__global__ __launch_bounds__(256) void crf_seg_maps(
    const unsigned char* __restrict__ bp, unsigned char* __restrict__ maps)
{
    const int b   = blockIdx.x >> 4;
    const int s   = blockIdx.x & 15;
    const int tid = threadIdx.x;
    const int rows = (s == NSEG - 1) ? SEGLEN - 1 : SEGLEN;
    const int r0   = s * SEGLEN;

    __shared__ unsigned char lbp[SEGLEN][CRF_K];   // 16 KB

    const unsigned char* bpb = bp + (size_t)b * (CRF_T - 1) * CRF_K;
    const int nw = rows * 64;
    for (int w = tid; w < nw; w += 256) {
        const int r = w >> 6, cc = w & 63;
        ((unsigned int*)lbp[r])[cc] =
            ((const unsigned int*)(bpb + (size_t)(r0 + r) * CRF_K))[cc];
    }
    __syncthreads();

    int tag = tid;
    for (int j = rows - 1; j >= 0; --j) tag = lbp[j][tag];
    maps[((size_t)b * NSEG + s) * CRF_K + tid] = (unsigned char)tag;
}

__global__ __launch_bounds__(256) void crf_compose(
    const float* __restrict__ M, const float* __restrict__ em,
    const unsigned char* __restrict__ maps,
    int* __restrict__ exits, float* __restrict__ out)
{
    const int b   = blockIdx.x;
    const int tid = threadIdx.x;

    __shared__ float s_wv[4];
    __shared__ int   s_wi[4];

    float v = M[((size_t)(CRF_T - 1) * CRF_B + b) * CRF_K + tid]
            + em[((size_t)b * CRF_T + (CRF_T - 1)) * CRF_K + tid];
    int   i = tid;
#pragma unroll
    for (int off = 32; off >= 1; off >>= 1) {
        float ov = __shfl_xor(v, off, 64);
        int   oi = __shfl_xor(i, off, 64);
        if (ov > v || (ov == v && oi < i)) { v = ov; i = oi; }
    }
    const int lane = tid & 63, wv = tid >> 6;
    if (lane == 0) { s_wv[wv] = v; s_wi[wv] = i; }
    __syncthreads();
    if (tid == 0) {
        float bv = s_wv[0]; int bi = s_wi[0];
#pragma unroll
        for (int w = 1; w < 4; ++w)
            if (s_wv[w] > bv) { bv = s_wv[w]; bi = s_wi[w]; }
        out[(size_t)b * CRF_T + (CRF_T - 1)] = (float)bi;
        int E = bi;
        exits[b * NSEG + NSEG - 1] = E;
        const unsigned char* mb = maps + (size_t)b * NSEG * CRF_K;
        for (int s = NSEG - 1; s >= 1; --s) {
            E = mb[(size_t)s * CRF_K + E];
            exits[b * NSEG + s - 1] = E;
        }
    }
}

__global__ __launch_bounds__(256) void crf_emit(
    const unsigned char* __restrict__ bp, const int* __restrict__ exits,
    float* __restrict__ out)
{
    const int b   = blockIdx.x >> 4;
    const int s   = blockIdx.x & 15;
    const int tid = threadIdx.x;
    const int rows = (s == NSEG - 1) ? SEGLEN - 1 : SEGLEN;
    const int r0   = s * SEGLEN;

    __shared__ unsigned char lbp[SEGLEN][CRF_K];

    const unsigned char* bpb = bp + (size_t)b * (CRF_T - 1) * CRF_K;
    const int nw = rows * 64;
    for (int w = tid; w < nw; w += 256) {
        const int r = w >> 6, cc = w & 63;
        ((unsigned int*)lbp[r])[cc] =
            ((const unsigned int*)(bpb + (size_t)(r0 + r) * CRF_K))[cc];
    }
    __syncthreads();

    int tag = tid;
    const bool win = (tid == exits[b * NSEG + s]);
    for (int j = rows - 1; j >= 0; --j) {
        tag = lbp[j][tag];
        if (win) out[(size_t)b * CRF_T + r0 + j] = (float)tag;
    }
}

__global__ void crf_zero_out(float* __restrict__ out, int n)
{
    int i = blockIdx.x * blockDim.x + threadIdx.x;
    if (i < n) out[i] = 0.0f;
}

// ---------------------------------------------------------------------------

extern "C" void kernel_launch(void* const* d_in, const int* in_sizes, int n_in,
                              void* d_out, int out_size, void* d_ws, size_t ws_size,
                              hipStream_t stream) {
    (void)in_sizes; (void)n_in;
    const float* em    = (const float*)d_in[0];   // [B,T,K]
    const float* trans = (const float*)d_in[1];   // [K,K]
    float* out = (float*)d_out;                   // [B,T]

    const size_t M_bytes     = (size_t)CRF_T * CRF_B * CRF_K * sizeof(float); // 64 MB
    const size_t gid_bytes   = (size_t)CRF_T * CRF_B * 128;                   // 8.4 MB
    const size_t bp_bytes    = (size_t)CRF_B * (CRF_T - 1) * CRF_K;           // 16.75 MB
    const size_t maps_bytes  = (size_t)CRF_B * NSEG * CRF_K;                  // 256 KB
    const size_t exits_bytes = (size_t)CRF_B * NSEG * sizeof(int);            // 4 KB

    char* w = (char*)d_ws;
    if (ws_size >= M_bytes + gid_bytes + bp_bytes + maps_bytes + exits_bytes) {
        float*         M     = (float*)w;            w += M_bytes;
        unsigned char* gidp  = (unsigned char*)w;    w += gid_bytes;
        unsigned char* bp    = (unsigned char*)w;    w += bp_bytes;
        unsigned char* maps  = (unsigned char*)w;    w += maps_bytes;
        int*           exits = (int*)w;

        crf_forward_states<<<CRF_B, 1024, 0, stream>>>(em, trans, M, gidp);
        crf_bp_gid<<<CRF_B * 8, 256, 0, stream>>>(M, em, trans, gidp, bp);
        crf_seg_maps<<<CRF_B * NSEG, 256, 0, stream>>>(bp, maps);
        crf_compose<<<CRF_B, 256, 0, stream>>>(M, em, maps, exits, out);
        crf_emit<<<CRF_B * NSEG, 256, 0, stream>>>(bp, exits, out);
    } else if (ws_size >= M_bytes + bp_bytes + maps_bytes + exits_bytes) {
        float*         M     = (float*)w;            w += M_bytes;
        unsigned char* bp    = (unsigned char*)w;    w += bp_bytes;
        unsigned char* maps  = (unsigned char*)w;    w += maps_bytes;
        int*           exits = (int*)w;

        crf_forward_states<<<CRF_B, 1024, 0, stream>>>(em, trans, M, nullptr);
        crf_bp_matrix<<<CRF_B * NSEG, 1024, 0, stream>>>(M, em, trans, bp);
        crf_seg_maps<<<CRF_B * NSEG, 256, 0, stream>>>(bp, maps);
        crf_compose<<<CRF_B, 256, 0, stream>>>(M, em, maps, exits, out);
        crf_emit<<<CRF_B * NSEG, 256, 0, stream>>>(bp, exits, out);
    } else {
        crf_zero_out<<<(out_size + 255) / 256, 256, 0, stream>>>(out, out_size);
    }
}